// Round 11
// baseline (5861.932 us; speedup 1.0000x reference)
//
#include <hip/hip_runtime.h>

constexpr int B = 32, L = 1024, D = 512, H = 512;

// ---- LDS byte offsets ----
// A tiles: [16 rows][512 k] bf16 (rows 8..15 permanently zero).
constexpr int AH_HI = 0;        // h hi
constexpr int AH_LO = 16384;    // h lo
constexpr int AX_OFF = 32768;   // x single bf16
// B tiles: [2 tiles][16 n][512 k] bf16. BH tile0=[Whz|Whr] tile1=[Whh|0];
// BX tile0=[Wxz|Wxr] tile1=[0|Wxh].
constexpr int BH_OFF = 49152;
constexpr int BX_OFF = 81920;
// C partials: [4 waves][2 tiles][8 m][17] f32
constexpr int CB_OFF = 114688;
constexpr size_t SMEM_BYTES = 119040;   // 116.25 KiB (proven territory)

// ---- workspace ----
// hrec: [parity(2)][ring(4)][member(64)][64] 8B records
//       {hi32: (bf16_hi<<16)|bf16_lo of h value, lo32: stamp}. 256 KiB.

typedef __attribute__((ext_vector_type(8))) short short8v;
typedef __attribute__((ext_vector_type(4))) float f32x4;
using ull = unsigned long long;

__device__ __forceinline__ unsigned short f2bf(float f) {   // RNE f32->bf16
    unsigned u = __float_as_uint(f);
    return (unsigned short)((u + 0x7FFFu + ((u >> 16) & 1u)) >> 16);
}
__device__ __forceinline__ float bf2f(unsigned short b) {
    return __uint_as_float((unsigned)b << 16);
}
// XOR-swizzled byte address within a [row][1024B] tile
__device__ __forceinline__ int aswz(int row, int kbyte) {
    return row * 1024 + (kbyte ^ ((row & 7) << 4));
}
__device__ __forceinline__ ull ld_rec(const ull* p) {
    return __hip_atomic_load(p, __ATOMIC_RELAXED, __HIP_MEMORY_SCOPE_AGENT);
}
__device__ __forceinline__ void st_rec(ull* p, ull v) {
    __hip_atomic_store(p, v, __ATOMIC_RELAXED, __HIP_MEMORY_SCOPE_AGENT);
}

__global__ __launch_bounds__(256, 1)
void gru_stamp(const float* __restrict__ x, const float* __restrict__ h0,
               const float* __restrict__ Wxz, const float* __restrict__ Whz,
               const float* __restrict__ bz,
               const float* __restrict__ Wxr, const float* __restrict__ Whr,
               const float* __restrict__ br,
               const float* __restrict__ Wxh, const float* __restrict__ Whh,
               const float* __restrict__ bh,
               float* __restrict__ out, ull* __restrict__ hrec)
{
    extern __shared__ char smem[];

    const int tid = threadIdx.x;
    const int bid = blockIdx.x;
    // XCD-affinity remap (R5, kept): ring g occupies XCD residues {g, g+4}
    const int g  = bid & 3;          // ring: batches g*8 .. g*8+7
    const int fc = bid >> 2;         // member: features fc*8 .. +7
    const int F0 = fc * 8;

    // ---- zero all LDS (A pad rows + B zero-blocks must stay zero) ----
    for (int i = tid; i < (int)(SMEM_BYTES / 16); i += 256)
        *(uint4*)(smem + i * 16) = make_uint4(0, 0, 0, 0);
    __syncthreads();

    // ---- one-time weight staging: bf16, swizzled [n][k] fragments ----
    {
        const float* WSET[2][3] = {{Whz, Whr, Whh}, {Wxz, Wxr, Wxh}};
        const int TB[2][3][2] = {{{0,0},{0,8},{1,0}}, {{0,0},{0,8},{1,8}}};
        for (int s = 0; s < 2; ++s) {
            const int bbase = (s == 0) ? BH_OFF : BX_OFF;
            for (int gi = 0; gi < 3; ++gi) {
                const float* W = WSET[s][gi];
                const int tile = TB[s][gi][0], nb = TB[s][gi][1];
                for (int dk = 0; dk < 2; ++dk) {
                    const int k = 2 * tid + dk;
                    const float* src = W + (size_t)k * H + F0;
                    const float4 a = *(const float4*)src;
                    const float4 bq = *(const float4*)(src + 4);
                    const float v[8] = {a.x, a.y, a.z, a.w, bq.x, bq.y, bq.z, bq.w};
#pragma unroll
                    for (int f = 0; f < 8; ++f)
                        *(unsigned short*)(smem + bbase + tile * 16384 +
                                           aswz(nb + f, k * 2)) = f2bf(v[f]);
                }
            }
        }
    }

    // ---- per-thread roles ----
    // x staging: row srow = tid&7 (bank-spread), 16 cols from scol
    const int srow = tid & 7;
    const int scol = (tid >> 3) * 16;
    // h ingest: member hm = tid>>2, quarter hq = tid&3 (16 records = 2 rows)
    const int hm = tid >> 2, hq = tid & 3;
    // MFMA: wave w, lane: rc = A-row / B-col, kb = k-block
    const int w    = tid >> 6;
    const int lane = tid & 63;
    const int rc   = lane & 15;
    const int kb   = lane >> 4;
    int offk[4];
#pragma unroll
    for (int ks = 0; ks < 4; ++ks)
        offk[ks] = aswz(rc, (w * 4 + ks) * 64 + kb * 16);
    // epilogue (4-wave): wave w, lanes 0..15 own pair p = w*16+lane
    const int p  = w * 16 + lane;         // valid when lane<16
    const int em = p >> 3, ef = p & 7;    // batch, feature
    float bzv = 0.f, brv = 0.f, bhv = 0.f, hold = 0.f;
    if (lane < 16) {
        bzv = bz[F0 + ef]; brv = br[F0 + ef]; bhv = bh[F0 + ef];
        hold = h0[(g * 8 + em) * H + F0 + ef];
        // publish h0 record: parity 0, stamp 1 — fire-and-forget, self-stamped
        const unsigned hi = f2bf(hold);
        const unsigned lo = f2bf(hold - bf2f((unsigned short)hi));
        const ull rec = ((ull)((hi << 16) | lo) << 32) | 1ull;
        st_rec(&hrec[((0 * 4 + (size_t)g) * 64 + fc) * 64 + p], rec);
    }

    // prefetch x(0)
    float4 xr[4];
    {
        const float* xp = x + ((size_t)(g * 8 + srow) * L + 0) * D + scol;
#pragma unroll
        for (int c = 0; c < 4; ++c) xr[c] = *(const float4*)(xp + 4 * c);
    }

    for (int t = 0; t < L; ++t) {
        // ---- stage x(t) as single bf16 (hides LDS work before the poll) ----
        {
            float xv[16];
#pragma unroll
            for (int c = 0; c < 4; ++c) {
                xv[4 * c + 0] = xr[c].x; xv[4 * c + 1] = xr[c].y;
                xv[4 * c + 2] = xr[c].z; xv[4 * c + 3] = xr[c].w;
            }
            unsigned wd[8];
#pragma unroll
            for (int j = 0; j < 8; ++j)
                wd[j] = (unsigned)f2bf(xv[2 * j]) |
                        ((unsigned)f2bf(xv[2 * j + 1]) << 16);
            *(uint4*)(smem + AX_OFF + aswz(srow, scol * 2)) =
                make_uint4(wd[0], wd[1], wd[2], wd[3]);
            *(uint4*)(smem + AX_OFF + aswz(srow, scol * 2 + 16)) =
                make_uint4(wd[4], wd[5], wd[6], wd[7]);
        }

        // ---- ingest h(t): sentinel poll, bulk load, verify stamps ----
        const unsigned want = (unsigned)(t + 1);
        ull qd[16];
        {
            const ull* rb = hrec + ((((size_t)(t & 1)) * 4 + g) * 64 + hm) * 64 + hq * 16;
            // phase 1: cheap sentinel spin (8 B per retry)
            for (;;) {
                qd[0] = ld_rec(rb);
                if ((unsigned)qd[0] == want) break;
                __builtin_amdgcn_s_sleep(1);
            }
            // phase 2: bulk load once, then re-load only stale records
#pragma unroll
            for (int i = 1; i < 16; ++i) qd[i] = ld_rec(rb + i);
            for (;;) {
                bool ok = true;
#pragma unroll
                for (int i = 1; i < 16; ++i) ok = ok && ((unsigned)qd[i] == want);
                if (ok) break;
                __builtin_amdgcn_s_sleep(1);
#pragma unroll
                for (int i = 1; i < 16; ++i)
                    if ((unsigned)qd[i] != want) qd[i] = ld_rec(rb + i);
            }
            // unpack the 16 verified values -> AH_HI / AH_LO rows 2hq, 2hq+1
#pragma unroll
            for (int rsel = 0; rsel < 2; ++rsel) {
                const int brow = 2 * hq + rsel;
                unsigned v[8];
#pragma unroll
                for (int f = 0; f < 8; ++f)
                    v[f] = (unsigned)(qd[rsel * 8 + f] >> 32);
                uint4 hi4, lo4;
                hi4.x = (v[0] >> 16) | (v[1] & 0xFFFF0000u);
                hi4.y = (v[2] >> 16) | (v[3] & 0xFFFF0000u);
                hi4.z = (v[4] >> 16) | (v[5] & 0xFFFF0000u);
                hi4.w = (v[6] >> 16) | (v[7] & 0xFFFF0000u);
                lo4.x = (v[0] & 0xFFFFu) | (v[1] << 16);
                lo4.y = (v[2] & 0xFFFFu) | (v[3] << 16);
                lo4.z = (v[4] & 0xFFFFu) | (v[5] << 16);
                lo4.w = (v[6] & 0xFFFFu) | (v[7] << 16);
                const int ad = aswz(brow, hm * 16);
                *(uint4*)(smem + AH_HI + ad) = hi4;
                *(uint4*)(smem + AH_LO + ad) = lo4;
            }
        }
        __syncthreads();   // sync A: all staging visible to all waves

        // ---- MFMA: 3 passes (h_hi, h_lo, x) × 2 N-tiles × 4 k-steps ----
        f32x4 acc0 = {0.f, 0.f, 0.f, 0.f}, acc1 = {0.f, 0.f, 0.f, 0.f};
        {
            const char* Ab[3] = {smem + AH_HI, smem + AH_LO, smem + AX_OFF};
            const char* Bb[3] = {smem + BH_OFF, smem + BH_OFF, smem + BX_OFF};
#pragma unroll
            for (int pi = 0; pi < 3; ++pi) {
#pragma unroll
                for (int ks = 0; ks < 4; ++ks) {
                    const short8v a  = *(const short8v*)(Ab[pi] + offk[ks]);
                    const short8v b0 = *(const short8v*)(Bb[pi] + offk[ks]);
                    const short8v b1 = *(const short8v*)(Bb[pi] + 16384 + offk[ks]);
                    acc0 = __builtin_amdgcn_mfma_f32_16x16x32_bf16(a, b0, acc0, 0, 0, 0);
                    acc1 = __builtin_amdgcn_mfma_f32_16x16x32_bf16(a, b1, acc1, 0, 0, 0);
                }
            }
        }
        // write partial C (valid rows 0..7 live in lanes 0..31)
        if (lane < 32) {
            float* cbp = (float*)(smem + CB_OFF) + w * 272;
            const int mb = (lane >> 4) * 4, col = lane & 15;
#pragma unroll
            for (int reg = 0; reg < 4; ++reg) {
                cbp[(mb + reg) * 17 + col]       = acc0[reg];
                cbp[136 + (mb + reg) * 17 + col] = acc1[reg];
            }
        }
        __syncthreads();   // sync B: all CB partials ready; all MFMA done

        // ---- epilogue: 4 waves in parallel, wave w finalizes 16 pairs ----
        float hnv = 0.f;
        if (lane < 16) {
            float zz = 0.f, rr = 0.f, chh = 0.f, cxx = 0.f;
            const float* cb0 = (const float*)(smem + CB_OFF);
#pragma unroll
            for (int ww = 0; ww < 4; ++ww) {
                const float* cw = cb0 + ww * 272 + em * 17;
                zz  += cw[ef];        rr  += cw[8 + ef];
                chh += cw[136 + ef];  cxx += cw[136 + 8 + ef];
            }
            const float z = 1.f / (1.f + __expf(-(zz + bzv)));
            const float r = 1.f / (1.f + __expf(-(rr + brv)));
            const float pre = cxx + r * (chh + bhv);
            const float e = __expf(-2.f * fabsf(pre));
            float th = (1.f - e) / (1.f + e);
            th = (pre < 0.f) ? -th : th;
            hnv = z * hold + (1.f - z) * th;
            hold = hnv;

            // publish h(t+1): parity (t+1)&1, stamp t+2 — single 8B store,
            // no drain, no flag; consumers verify the embedded stamp.
            const unsigned hi = f2bf(hnv);
            const unsigned lo = f2bf(hnv - bf2f((unsigned short)hi));
            const ull rec = ((ull)((hi << 16) | lo) << 32) | (ull)(unsigned)(t + 2);
            st_rec(&hrec[((((size_t)((t + 1) & 1)) * 4 + g) * 64 + fc) * 64 + p], rec);

            // out writes off the critical path
            out[((size_t)(g * 8 + em) * L + t) * H + F0 + ef] = hnv;
            if (t == L - 1)
                out[(size_t)B * L * H + (size_t)(g * 8 + em) * H + F0 + ef] = hnv;
        }

        // prefetch x(t+1); latency hides under next step's poll
        if (t + 1 < L) {
            const float* xp = x + ((size_t)(g * 8 + srow) * L + (t + 1)) * D + scol;
#pragma unroll
            for (int c = 0; c < 4; ++c) xr[c] = *(const float4*)(xp + 4 * c);
        }
        // AX/AH overwrite hazards for t+1 are covered by sync B (all MFMA of
        // step t complete before any wave proceeds); record freshness and
        // anti-overwrite are guaranteed by the stamp protocol (skew <= 1).
    }
}

extern "C" void kernel_launch(void* const* d_in, const int* in_sizes, int n_in,
                              void* d_out, int out_size, void* d_ws, size_t ws_size,
                              hipStream_t stream) {
    const float* x   = (const float*)d_in[0];
    const float* h0  = (const float*)d_in[1];
    const float* Wxz = (const float*)d_in[2];
    const float* Whz = (const float*)d_in[3];
    const float* bz  = (const float*)d_in[4];
    const float* Wxr = (const float*)d_in[5];
    const float* Whr = (const float*)d_in[6];
    const float* br  = (const float*)d_in[7];
    const float* Wxh = (const float*)d_in[8];
    const float* Whh = (const float*)d_in[9];
    const float* bh  = (const float*)d_in[10];
    float* out = (float*)d_out;
    ull* hrec = (ull*)d_ws;

    (void)hipFuncSetAttribute((const void*)gru_stamp,
                              hipFuncAttributeMaxDynamicSharedMemorySize,
                              (int)SMEM_BYTES);

    void* args[] = {(void*)&x, (void*)&h0, (void*)&Wxz, (void*)&Whz, (void*)&bz,
                    (void*)&Wxr, (void*)&Whr, (void*)&br, (void*)&Wxh, (void*)&Whh,
                    (void*)&bh, (void*)&out, (void*)&hrec};
    hipError_t err = hipLaunchCooperativeKernel((void*)gru_stamp, dim3(256),
                                                dim3(256), args,
                                                (unsigned)SMEM_BYTES, stream);
    if (err != hipSuccess) {
        // kernel uses only its own stamp protocol; 256 blocks at 1/CU are
        // trivially co-resident, so a plain launch is a safe fallback
        gru_stamp<<<dim3(256), dim3(256), SMEM_BYTES, stream>>>(
            x, h0, Wxz, Whz, bz, Wxr, Whr, br, Wxh, Whh, bh, out, hrec);
    }
}

// Round 12
// 3035.798 us; speedup vs baseline: 1.9309x; 1.9309x over previous
//
#include <hip/hip_runtime.h>

constexpr int B = 32, L = 1024, D = 512, H = 512;

// ---- LDS byte offsets (R9-proven layout) ----
// A tiles [16 rows][512 k] bf16 — rows 0..3 = batches, rows 4..15 zero.
constexpr int AH_HI = 0;
constexpr int AH_LO = 16384;
constexpr int AX_OFF = 32768;
// B tiles [16 n][512 k] bf16 — n = member's 16 output features.
constexpr int BHZ = 49152, BHR = 65536, BHC = 81920;
constexpr int BXZ = 98304, BXR = 114688, BXC = 131072;
// C partials [4 waves][4 accs][4 m][17] f32
constexpr int CB_OFF = 147456;
constexpr size_t SMEM_BYTES = 151808;   // 148.25 KiB (launch-proven in R9)

// ---- workspace (dword offsets) ----
// hrec: [parity(2)][ring(8)][member(32)][64] u32 (hi16|lo16 bf16 of h)
constexpr int HREC_OFF = 0;          // 32768 dw = 128 KiB
constexpr int FLAGS_OFF = 32768;     // [ring(8)][member(32)] stride 32 dw;
                                     // dwords 0..3 of each line = wave flags

typedef __attribute__((ext_vector_type(8))) short short8v;
typedef __attribute__((ext_vector_type(4))) float f32x4;
using ull = unsigned long long;

__device__ __forceinline__ unsigned short f2bf(float f) {   // RNE f32->bf16
    unsigned u = __float_as_uint(f);
    return (unsigned short)((u + 0x7FFFu + ((u >> 16) & 1u)) >> 16);
}
__device__ __forceinline__ float bf2f(unsigned short b) {
    return __uint_as_float((unsigned)b << 16);
}
// XOR-swizzled byte address within a [row][1024B] tile
__device__ __forceinline__ int aswz(int row, int kbyte) {
    return row * 1024 + (kbyte ^ ((row & 7) << 4));
}
__device__ __forceinline__ ull ld_agent64(const ull* p) {
    return __hip_atomic_load(p, __ATOMIC_RELAXED, __HIP_MEMORY_SCOPE_AGENT);
}
__device__ __forceinline__ void st_agent32(unsigned* p, unsigned v) {
    __hip_atomic_store(p, v, __ATOMIC_RELAXED, __HIP_MEMORY_SCOPE_AGENT);
}

__global__ __launch_bounds__(256, 1)
void gru_r8(const float* __restrict__ x, const float* __restrict__ h0,
            const float* __restrict__ Wxz, const float* __restrict__ Whz,
            const float* __restrict__ bz,
            const float* __restrict__ Wxr, const float* __restrict__ Whr,
            const float* __restrict__ br,
            const float* __restrict__ Wxh, const float* __restrict__ Whh,
            const float* __restrict__ bh,
            float* __restrict__ out, unsigned* __restrict__ ws)
{
    extern __shared__ char smem[];

    const int tid = threadIdx.x;
    const int bid = blockIdx.x;
    // ring g = XCD residue (round-robin dispatch): all 32 members co-XCD,
    // so the shared x-slice lives in ONE L2. Sync still agent-scope (MALL).
    const int g  = bid & 7;          // ring: batches g*4 .. g*4+3
    const int fc = bid >> 3;         // member 0..31: features fc*16 .. +15
    const int F0 = fc * 16;

    unsigned* hrec  = ws + HREC_OFF;
    unsigned* fring = ws + FLAGS_OFF + g * 32 * 32;   // ring-local flag lines

    // ---- zero the A region (rows 4..15 must stay zero) ----
    for (int i = tid; i < 3072; i += 256)
        *(uint4*)(smem + i * 16) = make_uint4(0, 0, 0, 0);
    __syncthreads();

    // ---- one-time weight staging: 6 bf16 B-tiles, swizzled [n][k] ----
    {
        const float* WSRC[6] = {Whz, Whr, Whh, Wxz, Wxr, Wxh};
        const int    BOFF[6] = {BHZ, BHR, BHC, BXZ, BXR, BXC};
        for (int s6 = 0; s6 < 6; ++s6) {
            const float* W = WSRC[s6];
            char* bb = smem + BOFF[s6];
            for (int dk = 0; dk < 2; ++dk) {
                const int k = 2 * tid + dk;
                const float* src = W + (size_t)k * H + F0;
                const float4 a = *(const float4*)(src);
                const float4 b4 = *(const float4*)(src + 4);
                const float4 c4 = *(const float4*)(src + 8);
                const float4 d4 = *(const float4*)(src + 12);
                const float v[16] = {a.x, a.y, a.z, a.w, b4.x, b4.y, b4.z, b4.w,
                                     c4.x, c4.y, c4.z, c4.w, d4.x, d4.y, d4.z, d4.w};
#pragma unroll
                for (int f = 0; f < 16; ++f)
                    *(unsigned short*)(bb + aswz(f, k * 2)) = f2bf(v[f]);
            }
        }
    }

    // ---- per-thread roles ----
    // x staging: row xrow = tid&3 (ring-local batch), 8 cols from xcol
    const int xrow = tid & 3;
    const int xcol = (tid >> 2) * 8;
    // h ingest: member hm = tid>>3, chunk hc = tid&7 (8 records)
    const int hm = tid >> 3, hc = tid & 7;
    // MFMA: wave w covers K [w*128, +128); lane rc = A/B row, kb = 16B sub
    const int w    = tid >> 6;
    const int lane = tid & 63;
    const int rc   = lane & 15;
    const int kb   = lane >> 4;
    int offk[4];
#pragma unroll
    for (int ks = 0; ks < 4; ++ks)
        offk[ks] = aswz(rc, (w * 4 + ks) * 64 + kb * 16);
    // epilogue (4-wave): wave w, lanes 0..15 own output p = w*16+lane
    const int p  = w * 16 + lane;         // valid when lane<16
    const int em = p >> 4, ef = p & 15;   // batch (0..3), feature (0..15)
    float bzv = 0.f, brv = 0.f, bhv = 0.f, hold = 0.f;
    if (lane < 16) {
        bzv = bz[F0 + ef]; brv = br[F0 + ef]; bhv = bh[F0 + ef];
        hold = h0[(g * 4 + em) * H + F0 + ef];
        // publish initial packed record (parity 0)
        const unsigned hi = f2bf(hold);
        const unsigned lo = f2bf(hold - bf2f((unsigned short)hi));
        st_agent32(&hrec[((0 * 8 + g) * 32 + fc) * 64 + p], (hi << 16) | lo);
    }
    // per-wave drain, then each wave publishes its own flag = 1
    asm volatile("s_waitcnt vmcnt(0)" ::: "memory");
    if (lane == 0)
        st_agent32(&fring[fc * 32 + w], 1u);

    // prefetch x(0)
    float4 xq0, xq1;
    {
        const float* xp = x + ((size_t)(g * 4 + xrow) * L + 0) * D + xcol;
        xq0 = *(const float4*)(xp);
        xq1 = *(const float4*)(xp + 4);
    }

    for (int t = 0; t < L; ++t) {
        // ---- stage x(t) as bf16 into AX (before the poll) ----
        {
            const float xv[8] = {xq0.x, xq0.y, xq0.z, xq0.w,
                                 xq1.x, xq1.y, xq1.z, xq1.w};
            uint4 wd;
            wd.x = (unsigned)f2bf(xv[0]) | ((unsigned)f2bf(xv[1]) << 16);
            wd.y = (unsigned)f2bf(xv[2]) | ((unsigned)f2bf(xv[3]) << 16);
            wd.z = (unsigned)f2bf(xv[4]) | ((unsigned)f2bf(xv[5]) << 16);
            wd.w = (unsigned)f2bf(xv[6]) | ((unsigned)f2bf(xv[7]) << 16);
            *(uint4*)(smem + AX_OFF + aswz(xrow, xcol * 2)) = wd;
        }

        // ---- all-wave poll: lane l<32 watches member l's 4 wave-flags ----
        const unsigned s = (unsigned)(t + 1);
        {
            const ull* fp = (const ull*)(fring + (lane & 31) * 32);
            for (;;) {
                bool ok = true;
                if (lane < 32) {
                    const ull f01 = ld_agent64(fp);
                    const ull f23 = ld_agent64(fp + 1);
                    const unsigned a0 = (unsigned)f01, a1 = (unsigned)(f01 >> 32);
                    const unsigned a2 = (unsigned)f23, a3 = (unsigned)(f23 >> 32);
                    ok = ((a0 - s) <= 1u) && ((a1 - s) <= 1u) &&
                         ((a2 - s) <= 1u) && ((a3 - s) <= 1u);
                }
                if (__all(ok)) break;
                __builtin_amdgcn_s_sleep(1);
            }
        }
        // no sync: each wave has itself verified all members before staging

        // ---- ingest h(t): bulk-load 8 records/thread, unpack to LDS ----
        {
            const ull* rb = (const ull*)&hrec[(((t & 1) * 8 + g) * 32 + hm) * 64] + hc * 4;
            ull qd[4];
#pragma unroll
            for (int i = 0; i < 4; ++i) qd[i] = ld_agent64(rb + i);
            unsigned v[8];
#pragma unroll
            for (int f = 0; f < 8; ++f) {
                const ull qq = qd[f >> 1];
                v[f] = (f & 1) ? (unsigned)(qq >> 32) : (unsigned)qq;
            }
            uint4 hi4, lo4;
            hi4.x = (v[0] >> 16) | (v[1] & 0xFFFF0000u);
            hi4.y = (v[2] >> 16) | (v[3] & 0xFFFF0000u);
            hi4.z = (v[4] >> 16) | (v[5] & 0xFFFF0000u);
            hi4.w = (v[6] >> 16) | (v[7] & 0xFFFF0000u);
            lo4.x = (v[0] & 0xFFFFu) | (v[1] << 16);
            lo4.y = (v[2] & 0xFFFFu) | (v[3] << 16);
            lo4.z = (v[4] & 0xFFFFu) | (v[5] << 16);
            lo4.w = (v[6] & 0xFFFFu) | (v[7] << 16);
            // records hc*8..hc*8+7 of member hm = batch hc>>1,
            // features (hc&1)*8..+7 -> kbyte = hm*32 + (hc&1)*16
            const int brow  = hc >> 1;
            const int kbyte = hm * 32 + (hc & 1) * 16;
            *(uint4*)(smem + AH_HI + aswz(brow, kbyte)) = hi4;
            *(uint4*)(smem + AH_LO + aswz(brow, kbyte)) = lo4;
        }
        __syncthreads();   // sync A: all staging visible to all waves

        // ---- MFMA: 9 per k-step (h hi/lo + x across z,r,cand) × 4 ----
        f32x4 az = {0,0,0,0}, ar = {0,0,0,0}, ach = {0,0,0,0}, acx = {0,0,0,0};
#pragma unroll
        for (int ks = 0; ks < 4; ++ks) {
            const int o = offk[ks];
            const short8v ahh = *(const short8v*)(smem + AH_HI + o);
            const short8v ahl = *(const short8v*)(smem + AH_LO + o);
            const short8v axv = *(const short8v*)(smem + AX_OFF + o);
            const short8v bz_ = *(const short8v*)(smem + BHZ + o);
            const short8v br_ = *(const short8v*)(smem + BHR + o);
            const short8v bc_ = *(const short8v*)(smem + BHC + o);
            const short8v xz_ = *(const short8v*)(smem + BXZ + o);
            const short8v xr_ = *(const short8v*)(smem + BXR + o);
            const short8v xc_ = *(const short8v*)(smem + BXC + o);
            az  = __builtin_amdgcn_mfma_f32_16x16x32_bf16(ahh, bz_, az, 0, 0, 0);
            az  = __builtin_amdgcn_mfma_f32_16x16x32_bf16(ahl, bz_, az, 0, 0, 0);
            az  = __builtin_amdgcn_mfma_f32_16x16x32_bf16(axv, xz_, az, 0, 0, 0);
            ar  = __builtin_amdgcn_mfma_f32_16x16x32_bf16(ahh, br_, ar, 0, 0, 0);
            ar  = __builtin_amdgcn_mfma_f32_16x16x32_bf16(ahl, br_, ar, 0, 0, 0);
            ar  = __builtin_amdgcn_mfma_f32_16x16x32_bf16(axv, xr_, ar, 0, 0, 0);
            ach = __builtin_amdgcn_mfma_f32_16x16x32_bf16(ahh, bc_, ach, 0, 0, 0);
            ach = __builtin_amdgcn_mfma_f32_16x16x32_bf16(ahl, bc_, ach, 0, 0, 0);
            acx = __builtin_amdgcn_mfma_f32_16x16x32_bf16(axv, xc_, acx, 0, 0, 0);
        }
        // C partials: rows 0..3 (= batches) live in lanes 0..15, reg = row
        if (lane < 16) {
            float* cb = (float*)(smem + CB_OFF) + w * 272;
#pragma unroll
            for (int reg = 0; reg < 4; ++reg) {
                cb[(0 * 4 + reg) * 17 + lane] = az[reg];
                cb[(1 * 4 + reg) * 17 + lane] = ar[reg];
                cb[(2 * 4 + reg) * 17 + lane] = ach[reg];
                cb[(3 * 4 + reg) * 17 + lane] = acx[reg];
            }
        }
        __syncthreads();   // sync B: all CB partials ready; all MFMA done

        // ---- epilogue: 4 waves in parallel, wave w finalizes 16 outputs ----
        float hnv = 0.f;
        if (lane < 16) {
            const float* cb0 = (const float*)(smem + CB_OFF);
            float zz = 0.f, rr = 0.f, chh = 0.f, cxx = 0.f;
#pragma unroll
            for (int ww = 0; ww < 4; ++ww) {
                const float* cw = cb0 + ww * 272;
                zz  += cw[(0 * 4 + em) * 17 + ef];
                rr  += cw[(1 * 4 + em) * 17 + ef];
                chh += cw[(2 * 4 + em) * 17 + ef];
                cxx += cw[(3 * 4 + em) * 17 + ef];
            }
            const float z = 1.f / (1.f + __expf(-(zz + bzv)));
            const float r = 1.f / (1.f + __expf(-(rr + brv)));
            const float pre = cxx + r * (chh + bhv);
            const float e = __expf(-2.f * fabsf(pre));
            float th = (1.f - e) / (1.f + e);
            th = (pre < 0.f) ? -th : th;
            hnv = z * hold + (1.f - z) * th;
            hold = hnv;

            const unsigned hi = f2bf(hnv);
            const unsigned lo = f2bf(hnv - bf2f((unsigned short)hi));
            st_agent32(&hrec[((((t + 1) & 1) * 8 + g) * 32 + fc) * 64 + p],
                       (hi << 16) | lo);
        }
        // per-wave drain of this wave's record stores, then its own flag
        asm volatile("s_waitcnt vmcnt(0)" ::: "memory");
        if (lane == 0)
            st_agent32(&fring[fc * 32 + w], s + 1u);

        // out writes off the critical path
        if (lane < 16) {
            out[((size_t)(g * 4 + em) * L + t) * H + F0 + ef] = hnv;
            if (t == L - 1)
                out[(size_t)B * L * H + (size_t)(g * 4 + em) * H + F0 + ef] = hnv;
        }

        // prefetch x(t+1); latency hides under next step's poll
        if (t + 1 < L) {
            const float* xp = x + ((size_t)(g * 4 + xrow) * L + (t + 1)) * D + xcol;
            xq0 = *(const float4*)(xp);
            xq1 = *(const float4*)(xp + 4);
        }
        // AX/AH overwrite hazards for t+1 are covered by sync B (all MFMA of
        // step t complete before any wave proceeds); record freshness by the
        // window flag protocol (skew <= 1).
    }
}

extern "C" void kernel_launch(void* const* d_in, const int* in_sizes, int n_in,
                              void* d_out, int out_size, void* d_ws, size_t ws_size,
                              hipStream_t stream) {
    const float* x   = (const float*)d_in[0];
    const float* h0  = (const float*)d_in[1];
    const float* Wxz = (const float*)d_in[2];
    const float* Whz = (const float*)d_in[3];
    const float* bz  = (const float*)d_in[4];
    const float* Wxr = (const float*)d_in[5];
    const float* Whr = (const float*)d_in[6];
    const float* br  = (const float*)d_in[7];
    const float* Wxh = (const float*)d_in[8];
    const float* Whh = (const float*)d_in[9];
    const float* bh  = (const float*)d_in[10];
    float* out = (float*)d_out;
    unsigned* ws = (unsigned*)d_ws;

    (void)hipFuncSetAttribute((const void*)gru_r8,
                              hipFuncAttributeMaxDynamicSharedMemorySize,
                              (int)SMEM_BYTES);

    void* args[] = {(void*)&x, (void*)&h0, (void*)&Wxz, (void*)&Whz, (void*)&bz,
                    (void*)&Wxr, (void*)&Whr, (void*)&br, (void*)&Wxh, (void*)&Whh,
                    (void*)&bh, (void*)&out, (void*)&ws};
    hipError_t err = hipLaunchCooperativeKernel((void*)gru_r8, dim3(256),
                                                dim3(256), args,
                                                (unsigned)SMEM_BYTES, stream);
    if (err != hipSuccess) {
        // kernel uses only its own flag barrier; 256 blocks at 1/CU are
        // trivially co-resident, so a plain launch is a safe fallback
        gru_r8<<<dim3(256), dim3(256), SMEM_BYTES, stream>>>(
            x, h0, Wxz, Whz, bz, Wxr, Whr, br, Wxh, Whh, bh, out, ws);
    }
}

// Round 13
// 2917.498 us; speedup vs baseline: 2.0092x; 1.0405x over previous
//
#include <hip/hip_runtime.h>

constexpr int B = 32, L = 1024, D = 512, H = 512;

// ---- LDS byte offsets (R9-proven layout) ----
// A tiles [16 rows][512 k] bf16 — rows 0..3 = batches, rows 4..15 zero.
constexpr int AH_HI = 0;
constexpr int AH_LO = 16384;
constexpr int AX_OFF = 32768;
// B tiles [16 n][512 k] bf16 — n = member's 16 output features.
constexpr int BHZ = 49152, BHR = 65536, BHC = 81920;
constexpr int BXZ = 98304, BXR = 114688, BXC = 131072;
// C partials [4 waves][4 accs][4 m][17] f32
constexpr int CB_OFF = 147456;
constexpr size_t SMEM_BYTES = 151808;   // 148.25 KiB (launch-proven)

// ---- workspace (dword offsets) ----
// hrec: [parity(2)][ring(8)][member(32)][64] u32 (hi16|lo16 bf16 of h)
constexpr int HREC_OFF = 0;          // 32768 dw = 128 KiB
constexpr int FLAGS_OFF = 32768;     // [ring(8)][member(32)] stride 32 dw;
                                     // dwords 0..3 of each line = wave flags

typedef __attribute__((ext_vector_type(8))) short short8v;
typedef __attribute__((ext_vector_type(4))) float f32x4;
using ull = unsigned long long;

__device__ __forceinline__ unsigned short f2bf(float f) {   // RNE f32->bf16
    unsigned u = __float_as_uint(f);
    return (unsigned short)((u + 0x7FFFu + ((u >> 16) & 1u)) >> 16);
}
__device__ __forceinline__ float bf2f(unsigned short b) {
    return __uint_as_float((unsigned)b << 16);
}
// XOR-swizzled byte address within a [row][1024B] tile
__device__ __forceinline__ int aswz(int row, int kbyte) {
    return row * 1024 + (kbyte ^ ((row & 7) << 4));
}
__device__ __forceinline__ ull ld_agent64(const ull* p) {
    return __hip_atomic_load(p, __ATOMIC_RELAXED, __HIP_MEMORY_SCOPE_AGENT);
}
__device__ __forceinline__ void st_agent32(unsigned* p, unsigned v) {
    __hip_atomic_store(p, v, __ATOMIC_RELAXED, __HIP_MEMORY_SCOPE_AGENT);
}

__global__ __launch_bounds__(256, 1)
void gru_pm(const float* __restrict__ x, const float* __restrict__ h0,
            const float* __restrict__ Wxz, const float* __restrict__ Whz,
            const float* __restrict__ bz,
            const float* __restrict__ Wxr, const float* __restrict__ Whr,
            const float* __restrict__ br,
            const float* __restrict__ Wxh, const float* __restrict__ Whh,
            const float* __restrict__ bh,
            float* __restrict__ out, unsigned* __restrict__ ws)
{
    extern __shared__ char smem[];

    const int tid = threadIdx.x;
    const int bid = blockIdx.x;
    // ring g = XCD residue (round-robin dispatch): all 32 members co-XCD,
    // so the shared x-slice lives in ONE L2. Sync via agent scope (MALL).
    const int g  = bid & 7;          // ring: batches g*4 .. g*4+3
    const int fc = bid >> 3;         // member 0..31: features fc*16 .. +15
    const int F0 = fc * 16;

    unsigned* hrec  = ws + HREC_OFF;
    unsigned* fring = ws + FLAGS_OFF + g * 32 * 32;   // ring-local flag lines

    // ---- zero the A region (rows 4..15 must stay zero) ----
    for (int i = tid; i < 3072; i += 256)
        *(uint4*)(smem + i * 16) = make_uint4(0, 0, 0, 0);
    __syncthreads();

    // ---- one-time weight staging: 6 bf16 B-tiles, swizzled [n][k] ----
    {
        const float* WSRC[6] = {Whz, Whr, Whh, Wxz, Wxr, Wxh};
        const int    BOFF[6] = {BHZ, BHR, BHC, BXZ, BXR, BXC};
        for (int s6 = 0; s6 < 6; ++s6) {
            const float* W = WSRC[s6];
            char* bb = smem + BOFF[s6];
            for (int dk = 0; dk < 2; ++dk) {
                const int k = 2 * tid + dk;
                const float* src = W + (size_t)k * H + F0;
                const float4 a = *(const float4*)(src);
                const float4 b4 = *(const float4*)(src + 4);
                const float4 c4 = *(const float4*)(src + 8);
                const float4 d4 = *(const float4*)(src + 12);
                const float v[16] = {a.x, a.y, a.z, a.w, b4.x, b4.y, b4.z, b4.w,
                                     c4.x, c4.y, c4.z, c4.w, d4.x, d4.y, d4.z, d4.w};
#pragma unroll
                for (int f = 0; f < 16; ++f)
                    *(unsigned short*)(bb + aswz(f, k * 2)) = f2bf(v[f]);
            }
        }
    }

    // ---- per-thread roles ----
    // x staging: row xrow = tid&3 (ring-local batch), 8 cols from xcol
    const int xrow = tid & 3;
    const int xcol = (tid >> 2) * 8;
    // h ingest: member hm = tid>>3, chunk hc = tid&7 (8 records)
    const int hm = tid >> 3, hc = tid & 7;
    // MFMA: wave w covers K [w*128, +128); lane rc = A/B row, kb = 16B sub
    const int w    = tid >> 6;
    const int lane = tid & 63;
    const int rc   = lane & 15;
    const int kb   = lane >> 4;
    int offk[4];
#pragma unroll
    for (int ks = 0; ks < 4; ++ks)
        offk[ks] = aswz(rc, (w * 4 + ks) * 64 + kb * 16);
    // epilogue (4-wave): wave w, lanes 0..15 own output p = w*16+lane
    const int p  = w * 16 + lane;         // valid when lane<16
    const int em = p >> 4, ef = p & 15;   // batch (0..3), feature (0..15)
    float bzv = 0.f, brv = 0.f, bhv = 0.f, hold = 0.f;
    if (lane < 16) {
        bzv = bz[F0 + ef]; brv = br[F0 + ef]; bhv = bh[F0 + ef];
        hold = h0[(g * 4 + em) * H + F0 + ef];
        // publish initial packed record (parity 0)
        const unsigned hi = f2bf(hold);
        const unsigned lo = f2bf(hold - bf2f((unsigned short)hi));
        st_agent32(&hrec[((0 * 8 + g) * 32 + fc) * 64 + p], (hi << 16) | lo);
    }
    // per-wave drain, then each wave publishes its own flag = 1
    asm volatile("s_waitcnt vmcnt(0)" ::: "memory");
    if (lane == 0)
        st_agent32(&fring[fc * 32 + w], 1u);

    // prefetch x(0)
    float4 xq0, xq1;
    {
        const float* xp = x + ((size_t)(g * 4 + xrow) * L + 0) * D + xcol;
        xq0 = *(const float4*)(xp);
        xq1 = *(const float4*)(xp + 4);
    }

    for (int t = 0; t < L; ++t) {
        // ---- stage x(t) as bf16 into AX (absorbed by the poll wait) ----
        {
            const float xv[8] = {xq0.x, xq0.y, xq0.z, xq0.w,
                                 xq1.x, xq1.y, xq1.z, xq1.w};
            uint4 wd;
            wd.x = (unsigned)f2bf(xv[0]) | ((unsigned)f2bf(xv[1]) << 16);
            wd.y = (unsigned)f2bf(xv[2]) | ((unsigned)f2bf(xv[3]) << 16);
            wd.z = (unsigned)f2bf(xv[4]) | ((unsigned)f2bf(xv[5]) << 16);
            wd.w = (unsigned)f2bf(xv[6]) | ((unsigned)f2bf(xv[7]) << 16);
            *(uint4*)(smem + AX_OFF + aswz(xrow, xcol * 2)) = wd;
        }

        // ---- per-member decoupled ingest: each thread polls ONLY its own
        //      member hm; the moment hm is fresh it issues its 32B record
        //      load (early members' loads fly while late members settle).
        //      Full-barrier property restored by sync A below. ----
        const unsigned s = (unsigned)(t + 1);
        ull qd[4];
        {
            const ull* fp = (const ull*)(fring + hm * 32);
            const ull* rb = (const ull*)&hrec[(((t & 1) * 8 + g) * 32 + hm) * 64] + hc * 4;
            bool pending = true;
            do {
                if (pending) {
                    const ull f01 = ld_agent64(fp);
                    const ull f23 = ld_agent64(fp + 1);
                    const unsigned a0 = (unsigned)f01, a1 = (unsigned)(f01 >> 32);
                    const unsigned a2 = (unsigned)f23, a3 = (unsigned)(f23 >> 32);
                    if (((a0 - s) <= 1u) && ((a1 - s) <= 1u) &&
                        ((a2 - s) <= 1u) && ((a3 - s) <= 1u)) {
                        qd[0] = ld_agent64(rb + 0);
                        qd[1] = ld_agent64(rb + 1);
                        qd[2] = ld_agent64(rb + 2);
                        qd[3] = ld_agent64(rb + 3);
                        pending = false;
                    }
                }
            } while (__any(pending));
        }
        // unpack 8 records -> AH_HI/AH_LO
        {
            unsigned v[8];
#pragma unroll
            for (int f = 0; f < 8; ++f) {
                const ull qq = qd[f >> 1];
                v[f] = (f & 1) ? (unsigned)(qq >> 32) : (unsigned)qq;
            }
            uint4 hi4, lo4;
            hi4.x = (v[0] >> 16) | (v[1] & 0xFFFF0000u);
            hi4.y = (v[2] >> 16) | (v[3] & 0xFFFF0000u);
            hi4.z = (v[4] >> 16) | (v[5] & 0xFFFF0000u);
            hi4.w = (v[6] >> 16) | (v[7] & 0xFFFF0000u);
            lo4.x = (v[0] & 0xFFFFu) | (v[1] << 16);
            lo4.y = (v[2] & 0xFFFFu) | (v[3] << 16);
            lo4.z = (v[4] & 0xFFFFu) | (v[5] << 16);
            lo4.w = (v[6] & 0xFFFFu) | (v[7] << 16);
            // records hc*8..+7 of member hm = batch hc>>1, feats (hc&1)*8..+7
            const int brow  = hc >> 1;
            const int kbyte = hm * 32 + (hc & 1) * 16;
            *(uint4*)(smem + AH_HI + aswz(brow, kbyte)) = hi4;
            *(uint4*)(smem + AH_LO + aswz(brow, kbyte)) = lo4;
        }
        __syncthreads();   // sync A: all members staged, visible to all waves

        // ---- MFMA: 9 per k-step (h hi/lo + x across z,r,cand) × 4 ----
        f32x4 az = {0,0,0,0}, ar = {0,0,0,0}, ach = {0,0,0,0}, acx = {0,0,0,0};
#pragma unroll
        for (int ks = 0; ks < 4; ++ks) {
            const int o = offk[ks];
            const short8v ahh = *(const short8v*)(smem + AH_HI + o);
            const short8v ahl = *(const short8v*)(smem + AH_LO + o);
            const short8v axv = *(const short8v*)(smem + AX_OFF + o);
            const short8v bz_ = *(const short8v*)(smem + BHZ + o);
            const short8v br_ = *(const short8v*)(smem + BHR + o);
            const short8v bc_ = *(const short8v*)(smem + BHC + o);
            const short8v xz_ = *(const short8v*)(smem + BXZ + o);
            const short8v xr_ = *(const short8v*)(smem + BXR + o);
            const short8v xc_ = *(const short8v*)(smem + BXC + o);
            az  = __builtin_amdgcn_mfma_f32_16x16x32_bf16(ahh, bz_, az, 0, 0, 0);
            az  = __builtin_amdgcn_mfma_f32_16x16x32_bf16(ahl, bz_, az, 0, 0, 0);
            az  = __builtin_amdgcn_mfma_f32_16x16x32_bf16(axv, xz_, az, 0, 0, 0);
            ar  = __builtin_amdgcn_mfma_f32_16x16x32_bf16(ahh, br_, ar, 0, 0, 0);
            ar  = __builtin_amdgcn_mfma_f32_16x16x32_bf16(ahl, br_, ar, 0, 0, 0);
            ar  = __builtin_amdgcn_mfma_f32_16x16x32_bf16(axv, xr_, ar, 0, 0, 0);
            ach = __builtin_amdgcn_mfma_f32_16x16x32_bf16(ahh, bc_, ach, 0, 0, 0);
            ach = __builtin_amdgcn_mfma_f32_16x16x32_bf16(ahl, bc_, ach, 0, 0, 0);
            acx = __builtin_amdgcn_mfma_f32_16x16x32_bf16(axv, xc_, acx, 0, 0, 0);
        }
        // C partials: rows 0..3 (= batches) live in lanes 0..15, reg = row
        if (lane < 16) {
            float* cb = (float*)(smem + CB_OFF) + w * 272;
#pragma unroll
            for (int reg = 0; reg < 4; ++reg) {
                cb[(0 * 4 + reg) * 17 + lane] = az[reg];
                cb[(1 * 4 + reg) * 17 + lane] = ar[reg];
                cb[(2 * 4 + reg) * 17 + lane] = ach[reg];
                cb[(3 * 4 + reg) * 17 + lane] = acx[reg];
            }
        }
        __syncthreads();   // sync B: all CB partials ready; all MFMA done

        // ---- epilogue: 4 waves in parallel, wave w finalizes 16 outputs ----
        float hnv = 0.f;
        if (lane < 16) {
            const float* cb0 = (const float*)(smem + CB_OFF);
            float zz = 0.f, rr = 0.f, chh = 0.f, cxx = 0.f;
#pragma unroll
            for (int ww = 0; ww < 4; ++ww) {
                const float* cw = cb0 + ww * 272;
                zz  += cw[(0 * 4 + em) * 17 + ef];
                rr  += cw[(1 * 4 + em) * 17 + ef];
                chh += cw[(2 * 4 + em) * 17 + ef];
                cxx += cw[(3 * 4 + em) * 17 + ef];
            }
            const float z = 1.f / (1.f + __expf(-(zz + bzv)));
            const float r = 1.f / (1.f + __expf(-(rr + brv)));
            const float pre = cxx + r * (chh + bhv);
            const float e = __expf(-2.f * fabsf(pre));
            float th = (1.f - e) / (1.f + e);
            th = (pre < 0.f) ? -th : th;
            hnv = z * hold + (1.f - z) * th;
            hold = hnv;

            const unsigned hi = f2bf(hnv);
            const unsigned lo = f2bf(hnv - bf2f((unsigned short)hi));
            st_agent32(&hrec[((((t + 1) & 1) * 8 + g) * 32 + fc) * 64 + p],
                       (hi << 16) | lo);
        }
        // per-wave drain of this wave's record stores, then its own flag
        asm volatile("s_waitcnt vmcnt(0)" ::: "memory");
        if (lane == 0)
            st_agent32(&fring[fc * 32 + w], s + 1u);

        // out writes off the critical path
        if (lane < 16) {
            out[((size_t)(g * 4 + em) * L + t) * H + F0 + ef] = hnv;
            if (t == L - 1)
                out[(size_t)B * L * H + (size_t)(g * 4 + em) * H + F0 + ef] = hnv;
        }

        // prefetch x(t+1); latency hides under next step's poll
        if (t + 1 < L) {
            const float* xp = x + ((size_t)(g * 4 + xrow) * L + (t + 1)) * D + xcol;
            xq0 = *(const float4*)(xp);
            xq1 = *(const float4*)(xp + 4);
        }
        // AX/AH overwrite hazards for t+1 are covered by sync B (all MFMA of
        // step t complete before any wave proceeds); record freshness by the
        // per-member window flag protocol (skew <= 1).
    }
}

extern "C" void kernel_launch(void* const* d_in, const int* in_sizes, int n_in,
                              void* d_out, int out_size, void* d_ws, size_t ws_size,
                              hipStream_t stream) {
    const float* x   = (const float*)d_in[0];
    const float* h0  = (const float*)d_in[1];
    const float* Wxz = (const float*)d_in[2];
    const float* Whz = (const float*)d_in[3];
    const float* bz  = (const float*)d_in[4];
    const float* Wxr = (const float*)d_in[5];
    const float* Whr = (const float*)d_in[6];
    const float* br  = (const float*)d_in[7];
    const float* Wxh = (const float*)d_in[8];
    const float* Whh = (const float*)d_in[9];
    const float* bh  = (const float*)d_in[10];
    float* out = (float*)d_out;
    unsigned* ws = (unsigned*)d_ws;

    (void)hipFuncSetAttribute((const void*)gru_pm,
                              hipFuncAttributeMaxDynamicSharedMemorySize,
                              (int)SMEM_BYTES);

    void* args[] = {(void*)&x, (void*)&h0, (void*)&Wxz, (void*)&Whz, (void*)&bz,
                    (void*)&Wxr, (void*)&Whr, (void*)&br, (void*)&Wxh, (void*)&Whh,
                    (void*)&bh, (void*)&out, (void*)&ws};
    hipError_t err = hipLaunchCooperativeKernel((void*)gru_pm, dim3(256),
                                                dim3(256), args,
                                                (unsigned)SMEM_BYTES, stream);
    if (err != hipSuccess) {
        // kernel uses only its own flag barrier; 256 blocks at 1/CU are
        // trivially co-resident, so a plain launch is a safe fallback
        gru_pm<<<dim3(256), dim3(256), SMEM_BYTES, stream>>>(
            x, h0, Wxz, Whz, bz, Wxr, Whr, br, Wxh, Whh, bh, out, ws);
    }
}